// Round 5
// baseline (269.493 us; speedup 1.0000x reference)
//
#include <hip/hip_runtime.h>

#define B_  4
#define D_  512
#define H_  8
#define DV_ 64
#define S_  2048
#define LOG2E 1.442695041f

typedef __bf16 bf16;
typedef bf16  bf16x8 __attribute__((ext_vector_type(8)));
typedef bf16  bf16x4 __attribute__((ext_vector_type(4)));
typedef float f32x4  __attribute__((ext_vector_type(4)));

#define MFMA(a, b, c) __builtin_amdgcn_mfma_f32_16x16x32_bf16((a), (b), (c), 0, 0, 0)

// async global->LDS, 16B per lane; LDS dest is wave-uniform base + lane*16
#define GLOAD_LDS(g, l)                                                     \
    __builtin_amdgcn_global_load_lds(                                       \
        (const __attribute__((address_space(1))) void*)(g),                 \
        (__attribute__((address_space(3))) void*)(l), 16, 0, 0)

// ---------------------------------------------------------------------------
// Kernel 1: prep = transpose x (B,D,S fp32 -> B,S,D bf16)  +  pack weights
// ---------------------------------------------------------------------------
__global__ __launch_bounds__(256) void prep(
    const float* __restrict__ x, const float* __restrict__ Wq,
    const float* __restrict__ Wk, const float* __restrict__ Wv,
    const float* __restrict__ W0, bf16* __restrict__ xb, bf16* __restrict__ Wb) {
    const int bid = blockIdx.x;
    if (bid < 4096) {                            // transpose part
        __shared__ float tile[32][33];
        const int sblk = bid % 64;               // S/32
        const int dblk = (bid / 64) % 16;        // D/32
        const int b    = bid / 1024;
        const int d0 = dblk * 32, s0 = sblk * 32;
        const int tx = threadIdx.x & 31;
        const int ty = threadIdx.x >> 5;         // 0..7
        const float* xp = x + (size_t)b * D_ * S_;
#pragma unroll
        for (int i = 0; i < 32; i += 8)
            tile[ty + i][tx] = xp[(size_t)(d0 + ty + i) * S_ + s0 + tx];
        __syncthreads();
        bf16* xbp = xb + ((size_t)b * S_ + s0) * D_ + d0;
#pragma unroll
        for (int i = 0; i < 32; i += 8)
            xbp[(size_t)(ty + i) * D_ + tx] = (bf16)tile[tx][ty + i];
    } else {                                     // weight-pack part: 256 blocks
        const int f0 = ((bid - 4096) * 256 + threadIdx.x) * 16;  // 0..1048560
        const int src = f0 >> 18;                // 262144 elems per matrix
        const int off = f0 & 262143;
        const float* W = (src == 0) ? Wq : (src == 1) ? Wk : (src == 2) ? Wv : W0;
        float4 v0 = *(const float4*)&W[off];
        float4 v1 = *(const float4*)&W[off + 4];
        float4 v2 = *(const float4*)&W[off + 8];
        float4 v3 = *(const float4*)&W[off + 12];
        bf16x8 h0 = {(bf16)v0.x, (bf16)v0.y, (bf16)v0.z, (bf16)v0.w,
                     (bf16)v1.x, (bf16)v1.y, (bf16)v1.z, (bf16)v1.w};
        bf16x8 h1 = {(bf16)v2.x, (bf16)v2.y, (bf16)v2.z, (bf16)v2.w,
                     (bf16)v3.x, (bf16)v3.y, (bf16)v3.z, (bf16)v3.w};
        *(bf16x8*)&Wb[f0]     = h0;
        *(bf16x8*)&Wb[f0 + 8] = h1;
    }
}

// ---------------------------------------------------------------------------
// Kernel 2: fused QKV GEMM, m97-style core (r1-verified). V stored transposed
// + key-swizzled (sigma) for flash's LDS-staged PV fragments. T1 XCD swizzle.
// ---------------------------------------------------------------------------
__global__ __launch_bounds__(256) void gemm_qkv(
    const bf16* __restrict__ A, const bf16* __restrict__ Wb,
    const float* __restrict__ bq, const float* __restrict__ bk,
    const float* __restrict__ bv,
    bf16* __restrict__ Q, bf16* __restrict__ K, bf16* __restrict__ Vt) {
    __shared__ union {
        struct { bf16 A[8192]; bf16 B[8192]; } s;
        bf16 T[128][132];                        // epilogue transpose (33792 B)
    } sm;

    const int tid = threadIdx.x;
    const int w = tid >> 6, lane = tid & 63;
    const int m16 = lane & 15, quad = lane >> 4;
    const int wr = w & 1, wc = w >> 1;

    const int bid  = (blockIdx.x & 7) * 96 + (blockIdx.x >> 3);  // T1 swizzle
    const int nblk = bid % 12;                   // N = 1536 / 128
    const int mblk = bid / 12;                   // M = 8192 / 128
    const int m0 = mblk * 128, n0 = nblk * 128;

    f32x4 acc[4][4];
#pragma unroll
    for (int i = 0; i < 4; ++i)
#pragma unroll
        for (int j = 0; j < 4; ++j) acc[i][j] = (f32x4){0.f, 0.f, 0.f, 0.f};

    for (int k0 = 0; k0 < D_; k0 += 64) {
        __syncthreads();
#pragma unroll
        for (int i = 0; i < 4; ++i) {            // wave w stages chunks w*4..w*4+3
            const int c  = w * 4 + i;
            const int mt = c >> 1, kk = c & 1;
            const int row = mt * 16 + m16;
            const int col = k0 + kk * 32 + quad * 8;
            GLOAD_LDS(&A[(size_t)(m0 + row) * D_ + col],  &sm.s.A[(c * 64 + lane) * 8]);
            GLOAD_LDS(&Wb[(size_t)(n0 + row) * D_ + col], &sm.s.B[(c * 64 + lane) * 8]);
        }
        __syncthreads();
#pragma unroll
        for (int kk = 0; kk < 2; ++kk) {
            bf16x8 af[4], bfv[4];
#pragma unroll
            for (int t = 0; t < 4; ++t) {
                af[t]  = *(const bf16x8*)&sm.s.A[(((wr * 4 + t) * 2 + kk) * 64 + lane) * 8];
                bfv[t] = *(const bf16x8*)&sm.s.B[(((wc * 4 + t) * 2 + kk) * 64 + lane) * 8];
            }
#pragma unroll
            for (int mt = 0; mt < 4; ++mt)
#pragma unroll
                for (int nt = 0; nt < 4; ++nt)
                    acc[mt][nt] = MFMA(af[mt], bfv[nt], acc[mt][nt]);
        }
    }

    const int proj = n0 >> 9;                    // 128-tiles never straddle
    const float* bias = (proj == 0) ? bq : (proj == 1) ? bk : bv;

    if (proj == 2) {                             // V: direct sigma-swizzled store
#pragma unroll
        for (int mt = 0; mt < 4; ++mt)
#pragma unroll
            for (int nt = 0; nt < 4; ++nt) {
                const int nr = (n0 + wc * 64 + nt * 16 + m16) & 511;
                const int h = nr >> 6, e = nr & 63;
                const float bia = bias[nr];
                const int srow = m0 + wr * 64 + mt * 16 + quad * 4;
                const int b = srow >> 11, s = srow & 2047;
                const int s2 = (s & ~31) | (quad * 8 + (mt & 1) * 4);  // sigma
                bf16x4 hv;
#pragma unroll
                for (int r = 0; r < 4; ++r) hv[r] = (bf16)(acc[mt][nt][r] + bia);
                *(bf16x4*)&Vt[(((size_t)b * H_ + h) * DV_ + e) * S_ + s2] = hv;
            }
    } else {                                     // Q/K: LDS transpose -> bf16x8
        __syncthreads();
#pragma unroll
        for (int mt = 0; mt < 4; ++mt)
#pragma unroll
            for (int nt = 0; nt < 4; ++nt) {
                const int nloc = wc * 64 + nt * 16 + m16;
                const float bia = bias[(n0 + nloc) & 511];
#pragma unroll
                for (int r = 0; r < 4; ++r)
                    sm.T[wr * 64 + mt * 16 + quad * 4 + r][nloc] =
                        (bf16)(acc[mt][nt][r] + bia);
            }
        __syncthreads();
        const int rloc = tid >> 1, cb = (tid & 1) * 64;
        const int M = m0 + rloc, b = M >> 11, s = M & 2047;
        const int nrb = (n0 + cb) & 511;
        const int h = nrb >> 6;
        bf16* dst = ((proj == 0) ? Q : K) + (((size_t)b * H_ + h) * S_ + s) * DV_;
#pragma unroll
        for (int u = 0; u < 8; ++u)
            *(bf16x8*)&dst[u * 8] = *(const bf16x8*)&sm.T[rloc][cb + u * 8];
    }
}

// ---------------------------------------------------------------------------
// Kernel 3: flash attention v10 — Q-SPLIT decomposition for occupancy.
//  THEORY (r4 counters): latency-bound, ~80% stall, occupancy pinned at
//  2 waves/SIMD by the key-split wave's 64x64 output tile (o 64 + qf 32 +
//  lacc 16 regs) AND 72KB LDS. Q-split: wave owns 16 q-rows x all keys ->
//  o 16 + lacc 4 + qf 8 regs; K/V become block-SHARED dbuf LDS tiles
//  (KVBLK=64, staged once per block, same global traffic), 2-phase schedule
//  (STAGE(next) -> COMPUTE(cur) -> barrier). LDS 40960 B -> 3-4 blocks/CU.
//  Cross-wave O-reduction epilogue eliminated (wave owns whole q-rows);
//  wave-local LDS transpose coalesces the store, no barrier.
//  All permutation-sensitive pieces (sigma-V, XOR K-slot swizzle, exp2 mask,
//  frag conventions) carried over verbatim from the r4-verified kernel;
//  staging<->read slot identities re-derived: slot = p*64+lane both sides.
// ---------------------------------------------------------------------------
__global__ __launch_bounds__(256, 3) void flash_attn(
    const bf16* __restrict__ Q, const bf16* __restrict__ K, const bf16* __restrict__ Vt,
    const float* __restrict__ mask, bf16* __restrict__ heads) {
    __shared__ union {
        struct {
            bf16 Kl[2][2][2048];                 // [buf][half]: 32 keys x 64 d
            bf16 Vl[2][2][2048];                 // [buf][half]: 64 e x 32 keys
            float Ms[2048];                      // mask * log2(e)
        } s;                                     // 40960 B
        bf16 ep[4][16][72];                      // per-wave epilogue transpose
    } sm;

    // XCD-aware swizzle: contiguous 128-block chunk per XCD (K/V L2 locality)
    const int bid  = blockIdx.x;                 // B*H*(S/64) = 1024
    const int bidx = (bid & 7) * 128 + (bid >> 3);
    const int qblk = bidx & 31;
    const int h    = (bidx >> 5) & 7;
    const int b    = bidx >> 8;
    const int q0   = qblk * 64;

    const int tid = threadIdx.x;
    const int w = tid >> 6, lane = tid & 63;
    const int m16 = lane & 15, quad = lane >> 4;

    const bf16* Qp = Q  + ((size_t)b * H_ + h) * S_ * DV_;
    const bf16* Kp = K  + ((size_t)b * H_ + h) * S_ * DV_;
    const bf16* Vp = Vt + ((size_t)b * H_ + h) * DV_ * S_;
    const float* mp = mask + (size_t)b * S_;

    // per-lane staging constants (swizzle algebra, r1-verified)
    const int krow = lane >> 3;                          // 0..7
    const int kcol = ((lane & 7) ^ krow) * 8;            // elem offset in K row
    const int vrow = lane >> 2;                          // 0..15
    const int vcol = ((lane & 3) ^ (vrow & 3)) * 8;      // elem offset in V row
    const int sh  = w >> 1;                              // staging half
    const int sp0 = (w & 1) * 2;                         // staging p-pair base

// wave w stages 2 K-chunks + 2 V-chunks of half sh into buf NB (4 GLOADs)
#define STAGE(NB, T0)                                                        \
    {                                                                        \
        _Pragma("unroll")                                                    \
        for (int j = 0; j < 2; ++j) {                                        \
            const int p = sp0 + j;                                           \
            GLOAD_LDS(&Kp[(size_t)((T0) + sh * 32 + p * 8 + krow) * DV_ + kcol], \
                      &sm.s.Kl[NB][sh][(p * 64 + lane) * 8]);                \
        }                                                                    \
        _Pragma("unroll")                                                    \
        for (int j = 0; j < 2; ++j) {                                        \
            const int p = sp0 + j;                                           \
            GLOAD_LDS(&Vp[(size_t)(p * 16 + vrow) * S_ + (T0) + sh * 32 + vcol], \
                      &sm.s.Vl[NB][sh][(p * 64 + lane) * 8]);                \
        }                                                                    \
    }

    // stage mask to LDS pre-scaled into the exp2 domain (retires pre-barrier)
#pragma unroll
    for (int p = 0; p < 2; ++p) {
        const float4 mv = *(const float4*)&mp[(p * 256 + tid) * 4];
        f32x4 t = {mv.x * LOG2E, mv.y * LOG2E, mv.z * LOG2E, mv.w * LOG2E};
        *(f32x4*)&sm.s.Ms[(p * 256 + tid) * 4] = t;
    }

    // Q B-frags for this wave's 16 q-rows, pre-scaled by 1/8 (exact in bf16)
    bf16x8 qf[2];
#pragma unroll
    for (int kk = 0; kk < 2; ++kk) {
        bf16x8 v = *(const bf16x8*)&Qp[(size_t)(q0 + w * 16 + m16) * DV_ +
                                       kk * 32 + quad * 8];
#pragma unroll
        for (int i = 0; i < 8; ++i) v[i] = (bf16)((float)v[i] * 0.125f);
        qf[kk] = v;
    }

    bf16x8 ones;
#pragma unroll
    for (int i = 0; i < 8; ++i) ones[i] = (bf16)1.0f;

    f32x4 o[4];                                  // O^T[e=16mt+4quad+r][q=m16]
    f32x4 lacc = (f32x4){0.f, 0.f, 0.f, 0.f};
#pragma unroll
    for (int mt = 0; mt < 4; ++mt) o[mt] = (f32x4){0.f, 0.f, 0.f, 0.f};

    STAGE(0, 0);
    __syncthreads();                             // batch0 + mask visible

    for (int i = 0; i < 32; ++i) {
        const int buf = i & 1;
        if (i < 31) STAGE(buf ^ 1, (i + 1) * 64);
        const int t0 = i * 64;

        // QK^T (S^T trick): sc[kh*2+tt], lane = S[t=16(kh*2+tt)+4quad+r][q=m16]
        f32x4 sc[4];
#pragma unroll
        for (int kt = 0; kt < 4; ++kt) sc[kt] = (f32x4){0.f, 0.f, 0.f, 0.f};
#pragma unroll
        for (int kh = 0; kh < 2; ++kh)
#pragma unroll
            for (int tt = 0; tt < 2; ++tt)
#pragma unroll
                for (int kk = 0; kk < 2; ++kk) {
                    const bf16x8 kf = *(const bf16x8*)&sm.s.Kl[buf][kh][
                        ((tt * 16 + m16) * 8 + ((kk * 4 + quad) ^ (m16 & 7))) * 8];
                    sc[kh * 2 + tt] = MFMA(kf, qf[kk], sc[kh * 2 + tt]);
                }

        // mask + exp2 into PV B-frags (in-lane), then l and PV per key-half
        bf16x8 pf[2];
#pragma unroll
        for (int kh = 0; kh < 2; ++kh) {
            const f32x4 m2a = *(const f32x4*)&sm.s.Ms[t0 + kh * 32 + quad * 4];
            const f32x4 m2b = *(const f32x4*)&sm.s.Ms[t0 + kh * 32 + 16 + quad * 4];
#pragma unroll
            for (int r = 0; r < 4; ++r) {
                const float ngA = (m2a[r] - LOG2E) * 8e29f;  // 0 / -1.15e30
                const float ngB = (m2b[r] - LOG2E) * 8e29f;
                pf[kh][r]     = (bf16)__builtin_amdgcn_exp2f(
                    __builtin_fmaf(sc[kh * 2 + 0][r], m2a[r], ngA));
                pf[kh][4 + r] = (bf16)__builtin_amdgcn_exp2f(
                    __builtin_fmaf(sc[kh * 2 + 1][r], m2b[r], ngB));
            }
        }
#pragma unroll
        for (int kh = 0; kh < 2; ++kh) lacc = MFMA(ones, pf[kh], lacc);
#pragma unroll
        for (int kh = 0; kh < 2; ++kh)
#pragma unroll
            for (int mt = 0; mt < 4; ++mt) {
                const bf16x8 vf = *(const bf16x8*)&sm.s.Vl[buf][kh][
                    ((mt * 16 + m16) * 4 + (quad ^ (m16 & 3))) * 8];
                o[mt] = MFMA(vf, pf[kh], o[mt]);
            }

        __syncthreads();                         // stage(buf^1) done; buf free
    }

    // ---- epilogue: in-lane scale (q = m16 for both o and l), wave-local
    //      LDS transpose to coalesce the store. No barrier (post-loop sync).
    const float qm = mp[q0 + w * 16 + m16];
    const float inv = qm / lacc[0];
#pragma unroll
    for (int mt = 0; mt < 4; ++mt) {
        bf16x4 hv;
#pragma unroll
        for (int r = 0; r < 4; ++r) hv[r] = (bf16)(o[mt][r] * inv);
        *(bf16x4*)&sm.ep[w][m16][mt * 16 + quad * 4] = hv;
    }
    const int ql = lane >> 2, ec = (lane & 3) * 16;
    const bf16x8 h0 = *(const bf16x8*)&sm.ep[w][ql][ec];
    const bf16x8 h1 = *(const bf16x8*)&sm.ep[w][ql][ec + 8];
    bf16* dst = &heads[((size_t)b * S_ + q0 + w * 16 + ql) * D_ + h * DV_ + ec];
    *(bf16x8*)(dst)     = h0;
    *(bf16x8*)(dst + 8) = h1;
#undef STAGE
}

// ---------------------------------------------------------------------------
// Kernel 4: out projection (unchanged; T1 XCD swizzle)
// ---------------------------------------------------------------------------
__global__ __launch_bounds__(256) void gemm_out(
    const bf16* __restrict__ A, const bf16* __restrict__ Wb,
    const float* __restrict__ b0, float* __restrict__ outp) {
    __shared__ bf16 Asl[8192];
    __shared__ bf16 Bsl[8192];

    const int tid = threadIdx.x;
    const int w = tid >> 6, lane = tid & 63;
    const int m16 = lane & 15, quad = lane >> 4;
    const int wr = w & 1, wc = w >> 1;

    const int bid  = (blockIdx.x & 7) * 32 + (blockIdx.x >> 3);  // T1 swizzle
    const int nblk = bid & 3;                    // N = 512 / 128
    const int mblk = bid >> 2;                   // M = 8192 / 128
    const int m0 = mblk * 128, n0 = nblk * 128;

    f32x4 acc[4][4];
#pragma unroll
    for (int i = 0; i < 4; ++i)
#pragma unroll
        for (int j = 0; j < 4; ++j) acc[i][j] = (f32x4){0.f, 0.f, 0.f, 0.f};

    for (int k0 = 0; k0 < D_; k0 += 64) {
        __syncthreads();
#pragma unroll
        for (int i = 0; i < 4; ++i) {
            const int c  = w * 4 + i;
            const int mt = c >> 1, kk = c & 1;
            const int row = mt * 16 + m16;
            const int col = k0 + kk * 32 + quad * 8;
            GLOAD_LDS(&A[(size_t)(m0 + row) * D_ + col], &Asl[(c * 64 + lane) * 8]);
            GLOAD_LDS(&Wb[(size_t)(1536 + n0 + row) * D_ + col], &Bsl[(c * 64 + lane) * 8]);
        }
        __syncthreads();
#pragma unroll
        for (int kk = 0; kk < 2; ++kk) {
            bf16x8 af[4], bfv[4];
#pragma unroll
            for (int t = 0; t < 4; ++t) {
                af[t]  = *(const bf16x8*)&Asl[(((wr * 4 + t) * 2 + kk) * 64 + lane) * 8];
                bfv[t] = *(const bf16x8*)&Bsl[(((wc * 4 + t) * 2 + kk) * 64 + lane) * 8];
            }
#pragma unroll
            for (int mt = 0; mt < 4; ++mt)
#pragma unroll
                for (int nt = 0; nt < 4; ++nt)
                    acc[mt][nt] = MFMA(af[mt], bfv[nt], acc[mt][nt]);
        }
    }

#pragma unroll
    for (int mt = 0; mt < 4; ++mt)
#pragma unroll
        for (int nt = 0; nt < 4; ++nt) {
            const int n = n0 + wc * 64 + nt * 16 + m16;
            const float bia = b0[n];
            const int srow = m0 + wr * 64 + mt * 16 + quad * 4;
            const int b = srow >> 11, s = srow & 2047;
            float4 vv;
            vv.x = acc[mt][nt][0] + bia;
            vv.y = acc[mt][nt][1] + bia;
            vv.z = acc[mt][nt][2] + bia;
            vv.w = acc[mt][nt][3] + bia;
            *(float4*)&outp[((size_t)b * D_ + n) * S_ + s] = vv;
        }
}

// ---------------------------------------------------------------------------
extern "C" void kernel_launch(void* const* d_in, const int* in_sizes, int n_in,
                              void* d_out, int out_size, void* d_ws, size_t ws_size,
                              hipStream_t stream) {
    const float* x    = (const float*)d_in[0];
    const float* mask = (const float*)d_in[1];
    const float* Wq   = (const float*)d_in[2];
    const float* bq   = (const float*)d_in[3];
    const float* Wk   = (const float*)d_in[4];
    const float* bk   = (const float*)d_in[5];
    const float* Wv   = (const float*)d_in[6];
    const float* bv   = (const float*)d_in[7];
    const float* W0   = (const float*)d_in[8];
    const float* b0   = (const float*)d_in[9];
    float* out = (float*)d_out;

    char* ws = (char*)d_ws;
    const size_t SEG = (size_t)B_ * S_ * D_ * sizeof(bf16);   // 8 MiB
    bf16* xb    = (bf16*)(ws);            // reused as `heads` after gemm_qkv
    bf16* Qb    = (bf16*)(ws + SEG);
    bf16* Kb    = (bf16*)(ws + 2 * SEG);
    bf16* Vt    = (bf16*)(ws + 3 * SEG);
    bf16* Wb    = (bf16*)(ws + 4 * SEG);  // 2048x512 bf16 = 2 MiB
    bf16* heads = xb;

    prep<<<dim3(4096 + 256), dim3(256), 0, stream>>>(x, Wq, Wk, Wv, W0, xb, Wb);
    gemm_qkv<<<dim3(64 * 12), dim3(256), 0, stream>>>(xb, Wb, bq, bk, bv, Qb, Kb, Vt);
    flash_attn<<<dim3(B_ * H_ * (S_ / 64)), dim3(256), 0, stream>>>(Qb, Kb, Vt, mask, heads);
    gemm_out<<<dim3(64 * 4), dim3(256), 0, stream>>>(heads, Wb, b0, out);
}